// Round 1
// baseline (288.306 us; speedup 1.0000x reference)
//
#include <hip/hip_runtime.h>

// Dynamic per-pixel 5x5 conv (replicate pad) + leaky_relu(0.2).
// x: (N,C,H,W) f32; kernel: (N, C*25, H, W) f32; out: (N,C,H,W) f32.
// out[n,c,y,x] = sum_{k1,k2} xpad[n,c,y+k1,x+k2] * kern[n, c*25+k1*5+k2, y, x]

constexpr int N = 4, C = 8, H = 256, W = 256, K = 5, PAD = 2;
constexpr int HW = H * W;
constexpr float NEG_SLOPE = 0.2f;

__global__ __launch_bounds__(256) void dyn_conv5x5(
    const float* __restrict__ x,
    const float* __restrict__ kern,
    float* __restrict__ out) {
    // One thread = 4 consecutive pixels along w (a float4 quad).
    // tid layout: [nc(5b) | y(8b) | quad(6b)] ; W/4 = 64 quads per row.
    int tid = blockIdx.x * blockDim.x + threadIdx.x;
    int quad = tid & 63;           // 0..63
    int y    = (tid >> 6) & 255;   // 0..255
    int nc   = tid >> 14;          // 0..31 (n*C + c)
    int x0   = quad << 2;          // 0,4,...,252

    // kernel tensor: channel block for (n,c) is 25 contiguous HxW planes:
    // n*C*25 + c*25 = 25*nc.
    const float* kbase = kern + (size_t)(25 * nc) * HW + y * W + x0;
    const float* xbase = x + (size_t)nc * HW;

    float acc0 = 0.f, acc1 = 0.f, acc2 = 0.f, acc3 = 0.f;

    #pragma unroll
    for (int k1 = 0; k1 < K; ++k1) {
        int yy = y + k1 - PAD;
        yy = yy < 0 ? 0 : (yy > H - 1 ? H - 1 : yy);
        const float* xrow = xbase + yy * W;

        // 8-wide replicate-clamped window covering x0-2 .. x0+5
        float win[8];
        #pragma unroll
        for (int j = 0; j < 8; ++j) {
            int xx = x0 + j - PAD;
            xx = xx < 0 ? 0 : (xx > W - 1 ? W - 1 : xx);
            win[j] = xrow[xx];
        }

        #pragma unroll
        for (int k2 = 0; k2 < K; ++k2) {
            const float4 kv =
                *(const float4*)(kbase + (size_t)((k1 * K + k2)) * HW);
            acc0 = fmaf(kv.x, win[k2 + 0], acc0);
            acc1 = fmaf(kv.y, win[k2 + 1], acc1);
            acc2 = fmaf(kv.z, win[k2 + 2], acc2);
            acc3 = fmaf(kv.w, win[k2 + 3], acc3);
        }
    }

    float4 o;
    o.x = acc0 >= 0.f ? acc0 : NEG_SLOPE * acc0;
    o.y = acc1 >= 0.f ? acc1 : NEG_SLOPE * acc1;
    o.z = acc2 >= 0.f ? acc2 : NEG_SLOPE * acc2;
    o.w = acc3 >= 0.f ? acc3 : NEG_SLOPE * acc3;
    *(float4*)(out + (size_t)nc * HW + y * W + x0) = o;
}

extern "C" void kernel_launch(void* const* d_in, const int* in_sizes, int n_in,
                              void* d_out, int out_size, void* d_ws, size_t ws_size,
                              hipStream_t stream) {
    const float* x    = (const float*)d_in[0];
    const float* kern = (const float*)d_in[1];
    float* out        = (float*)d_out;

    constexpr int total_threads = N * C * H * (W / 4);  // 524288
    constexpr int block = 256;
    constexpr int grid = total_threads / block;         // 2048
    dyn_conv5x5<<<grid, block, 0, stream>>>(x, kern, out);
}

// Round 2
// 287.929 us; speedup vs baseline: 1.0013x; 1.0013x over previous
//
#include <hip/hip_runtime.h>

// Dynamic per-pixel 5x5 conv (replicate pad) + leaky_relu(0.2).
// x: (N,C,H,W) f32; kernel: (N, C*25, H, W) f32; out: (N,C,H,W) f32.
//
// Round 2: wave-covers-one-row design. Each thread owns 4 consecutive pixels
// (one float4). The 8-wide input window comes from the lane's own float4 plus
// 2 elements from each neighbor lane via __shfl (ds_bpermute, LDS pipe) —
// eliminating the 40 strided scalar x loads of round 1 and the win[8]
// register bloat that tanked occupancy. Kernel-tensor loads stay the pure
// exactly-once 16 B/lane coalesced stream.

constexpr int N = 4, C = 8, H = 256, W = 256, K = 5, PAD = 2;
constexpr int HW = H * W;
constexpr float NEG_SLOPE = 0.2f;

__global__ __launch_bounds__(256, 4) void dyn_conv5x5(
    const float* __restrict__ x,
    const float* __restrict__ kern,
    float* __restrict__ out) {
    // tid layout: [nc(5b) | y(8b) | quad(6b)] ; wave = one full row.
    int tid  = blockIdx.x * blockDim.x + threadIdx.x;
    int quad = tid & 63;           // lane within wave == quad within row
    int y    = (tid >> 6) & 255;
    int nc   = tid >> 14;          // n*C + c
    int x0   = quad << 2;

    const float* kbase = kern + (size_t)(25 * nc) * HW + y * W + x0;
    const float* xbase = x + (size_t)nc * HW;

    float acc0 = 0.f, acc1 = 0.f, acc2 = 0.f, acc3 = 0.f;

    #pragma unroll
    for (int k1 = 0; k1 < K; ++k1) {
        int yy = y + k1 - PAD;
        yy = yy < 0 ? 0 : (yy > H - 1 ? H - 1 : yy);

        // Own aligned float4: x[yy][x0 .. x0+3]
        const float4 b = *(const float4*)(xbase + yy * W + x0);

        // Window x[yy][x0-2 .. x0+5]:
        //   w0,w1 from left neighbor's .z,.w ; w6,w7 from right neighbor's .x,.y
        float w0 = __shfl_up(b.z, 1);
        float w1 = __shfl_up(b.w, 1);
        float w6 = __shfl_down(b.x, 1);
        float w7 = __shfl_down(b.y, 1);
        // replicate-pad fixup at row edges (per-lane cndmask, no branch)
        w0 = (quad == 0)  ? b.x : w0;
        w1 = (quad == 0)  ? b.x : w1;
        w6 = (quad == 63) ? b.w : w6;
        w7 = (quad == 63) ? b.w : w7;

        const float w8[8] = {w0, w1, b.x, b.y, b.z, b.w, w6, w7};

        #pragma unroll
        for (int k2 = 0; k2 < K; ++k2) {
            const float4 kv =
                *(const float4*)(kbase + (size_t)(k1 * K + k2) * HW);
            acc0 = fmaf(kv.x, w8[k2 + 0], acc0);
            acc1 = fmaf(kv.y, w8[k2 + 1], acc1);
            acc2 = fmaf(kv.z, w8[k2 + 2], acc2);
            acc3 = fmaf(kv.w, w8[k2 + 3], acc3);
        }
    }

    float4 o;
    o.x = acc0 >= 0.f ? acc0 : NEG_SLOPE * acc0;
    o.y = acc1 >= 0.f ? acc1 : NEG_SLOPE * acc1;
    o.z = acc2 >= 0.f ? acc2 : NEG_SLOPE * acc2;
    o.w = acc3 >= 0.f ? acc3 : NEG_SLOPE * acc3;
    *(float4*)(out + (size_t)nc * HW + y * W + x0) = o;
}

extern "C" void kernel_launch(void* const* d_in, const int* in_sizes, int n_in,
                              void* d_out, int out_size, void* d_ws, size_t ws_size,
                              hipStream_t stream) {
    const float* x    = (const float*)d_in[0];
    const float* kern = (const float*)d_in[1];
    float* out        = (float*)d_out;

    constexpr int total_threads = N * C * H * (W / 4);  // 524288
    constexpr int block = 256;
    constexpr int grid = total_threads / block;         // 2048
    dyn_conv5x5<<<grid, block, 0, stream>>>(x, kern, out);
}